// Round 8
// baseline (319.140 us; speedup 1.0000x reference)
//
#include <hip/hip_runtime.h>
#include <stdint.h>

typedef unsigned short u16;
typedef __attribute__((ext_vector_type(8))) short bf16x8;   // 8 bf16 = 4 VGPRs
typedef __attribute__((ext_vector_type(4))) float f32x4;

#define BATCH   4
#define CH      256
#define NPIX    4096      // 64*64
#define NGROUPS 32
#define CPG     8
#define EPS     1e-5f

#define NSPLIT 4
#define SPLEN  (NPIX / NSPLIT)
#define ATK    32
#define NIT    (SPLEN / ATK)     // 32
#define KSTR   264        // K LDS row stride: 2-way alias only, 16B aligned
#define VSTR   40         // Vt LDS row stride
#define PSTR   40
#define WSTR   264        // weight LDS row stride

// ---------- bf16 helpers ----------
__device__ __forceinline__ float bf2f(u16 u) {
    union { uint32_t i; float f; } v; v.i = ((uint32_t)u) << 16; return v.f;
}
__device__ __forceinline__ u16 f2bf(float f) {
    union { float f; uint32_t i; } v; v.f = f;
    uint32_t x = v.i;
    uint32_t r = (x + 0x7fffu + ((x >> 16) & 1u)) >> 16;
    return (u16)r;
}
__device__ __forceinline__ void unpack2(uint32_t u, float& a, float& b) {
    union { uint32_t i; float f; } lo, hi;
    lo.i = u << 16; hi.i = u & 0xffff0000u;
    a = lo.f; b = hi.f;
}
__device__ __forceinline__ void unpack8(uint4 u, float* f) {
    unpack2(u.x, f[0], f[1]); unpack2(u.y, f[2], f[3]);
    unpack2(u.z, f[4], f[5]); unpack2(u.w, f[6], f[7]);
}

// ---------- runtime input-dtype detection (fp32 vs bf16 ambiguity) ----------
__device__ __forceinline__ bool detect_f32(const void* xv) {
    const u16* p = (const u16*)xv;
    int bad = 0;
    #pragma unroll
    for (int i = 0; i < 32; i++) {
        u16 v = p[2 * i];
        int e = (v >> 7) & 0xff;
        bad += (e < 0x68 || e > 0x90) ? 1 : 0;
    }
    return bad >= 10;
}
__device__ __forceinline__ float load1(const void* b, size_t i, bool f32) {
    return f32 ? ((const float*)b)[i] : bf2f(((const u16*)b)[i]);
}
__device__ __forceinline__ void store1(void* b, size_t i, bool f32, float v) {
    if (f32) ((float*)b)[i] = v; else ((u16*)b)[i] = f2bf(v);
}
__device__ __forceinline__ void load4v(const void* base, size_t off, bool f32, float* f) {
    if (f32) {
        float4 a = *(const float4*)((const float*)base + off);
        f[0] = a.x; f[1] = a.y; f[2] = a.z; f[3] = a.w;
    } else {
        uint2 u = *(const uint2*)((const u16*)base + off);
        unpack2(u.x, f[0], f[1]); unpack2(u.y, f[2], f[3]);
    }
}
__device__ __forceinline__ void load8v(const void* base, size_t off, bool f32, float* f) {
    if (f32) {
        const float4* p = (const float4*)((const float*)base + off);
        float4 a = p[0], b = p[1];
        f[0] = a.x; f[1] = a.y; f[2] = a.z; f[3] = a.w;
        f[4] = b.x; f[5] = b.y; f[6] = b.z; f[7] = b.w;
    } else {
        uint4 u = *(const uint4*)((const u16*)base + off);
        unpack8(u, f);
    }
}

// ---------- K0: weights -> bf16 ----------
__global__ __launch_bounds__(256) void wconv(const void* __restrict__ qkv_w,
                                             const void* __restrict__ proj_w,
                                             u16* __restrict__ wq, u16* __restrict__ wp) {
    bool f32q = detect_f32(qkv_w);
    bool f32p = detect_f32(proj_w);
    int i = blockIdx.x * 256 + threadIdx.x;
    for (int e = i; e < 768 * 256; e += 256 * 256)
        wq[e] = f2bf(load1(qkv_w, e, f32q));
    for (int e = i; e < 256 * 256; e += 256 * 256)
        wp[e] = f2bf(load1(proj_w, e, f32p));
}

// ---------- K1: GroupNorm stats ----------
__global__ __launch_bounds__(256) void gn_stats(const void* __restrict__ x,
                                                float* __restrict__ stats, int b0) {
    bool f32 = detect_f32(x);
    int bg = b0 * NGROUPS + blockIdx.x;
    int t  = threadIdx.x;
    size_t base = (size_t)bg * (CPG * NPIX);
    float s = 0.f, s2 = 0.f;
    for (int i = t * 8; i < CPG * NPIX; i += 256 * 8) {
        float f[8]; load8v(x, base + i, f32, f);
        #pragma unroll
        for (int e = 0; e < 8; e++) { s += f[e]; s2 += f[e] * f[e]; }
    }
    #pragma unroll
    for (int off = 1; off < 64; off <<= 1) {
        s  += __shfl_xor(s,  off);
        s2 += __shfl_xor(s2, off);
    }
    __shared__ float red[8];
    int w = t >> 6;
    if ((t & 63) == 0) { red[w * 2] = s; red[w * 2 + 1] = s2; }
    __syncthreads();
    if (t == 0) {
        float S  = red[0] + red[2] + red[4] + red[6];
        float S2 = red[1] + red[3] + red[5] + red[7];
        float n  = (float)(CPG * NPIX);
        float mu = S / n;
        float var = S2 / n - mu * mu;
        stats[bg * 2]     = mu;
        stats[bg * 2 + 1] = rsqrtf(var + EPS);
    }
}

// ---------- K2: GN-apply + transpose: x[c][n] -> xt[n][c] normalized bf16 ----------
__global__ __launch_bounds__(256) void xgn(const void* __restrict__ x,
                                           const void* __restrict__ gn_w,
                                           const void* __restrict__ gn_b,
                                           const float* __restrict__ stats,
                                           u16* __restrict__ xt, int b0) {
    bool f32 = detect_f32(x);
    __shared__ u16 T[64][72];
    int bl = blockIdx.z, bg = b0 + bl;
    int n0 = blockIdx.x * 64, c0 = blockIdx.y * 64;
    int t = threadIdx.x;
    int tc = t >> 4, tn = (t & 15) * 4;
    #pragma unroll
    for (int i = 0; i < 4; i++) {
        int cl = tc + i * 16;
        int c = c0 + cl;
        int g = c >> 3;
        float mu = stats[(bg * NGROUPS + g) * 2];
        float rs = stats[(bg * NGROUPS + g) * 2 + 1];
        float wv = load1(gn_w, c, f32) * rs;
        float bv = load1(gn_b, c, f32) - mu * wv;
        float a[4];
        load4v(x, ((size_t)(bg * CH + c)) * NPIX + n0 + tn, f32, a);
        #pragma unroll
        for (int j = 0; j < 4; j++) T[cl][tn + j] = f2bf(a[j] * wv + bv);
    }
    __syncthreads();
    #pragma unroll
    for (int i = 0; i < 2; i++) {
        int e = t + i * 256;
        int nl = e >> 3, cc = (e & 7) * 8;
        union { uint4 v; u16 s[8]; } pk;
        #pragma unroll
        for (int j = 0; j < 8; j++) pk.s[j] = T[cc + j][nl];
        *(uint4*)(xt + ((size_t)(bl * NPIX) + n0 + nl) * CH + c0 + cc) = pk.v;
    }
}

// ---------- K3: QKV GEMM (MFMA; weights in LDS, A direct-global contiguous) ----------
__global__ __launch_bounds__(256, 4) void qkv_mfma(const u16* __restrict__ xt,
                                                   const u16* __restrict__ wq,
                                                   const void* __restrict__ qkv_b,
                                                   u16* __restrict__ qk,
                                                   u16* __restrict__ vt) {
    __shared__ u16 Ws[64 * WSTR];    // 33 KB
    bool f32b = detect_f32(qkv_b);
    int bl = blockIdx.z;
    int n0 = blockIdx.x * 128, o0 = blockIdx.y * 64;
    int t = threadIdx.x;
    int w = t >> 6, lane = t & 63;
    int l15 = lane & 15, quad = lane >> 4;
    int pbase = n0 + w * 32;

    #pragma unroll
    for (int i = 0; i < 8; i++) {
        int e = t + i * 256;
        *(uint4*)(Ws + (e >> 5) * WSTR + (e & 31) * 8) =
            *(const uint4*)(wq + (size_t)(o0 + (e >> 5)) * CH + (e & 31) * 8);
    }
    __syncthreads();

    const u16* xa = xt + ((size_t)(bl * NPIX + pbase)) * CH;
    f32x4 acc[2][4];
    #pragma unroll
    for (int m = 0; m < 2; m++)
        #pragma unroll
        for (int n = 0; n < 4; n++)
            #pragma unroll
            for (int r = 0; r < 4; r++) acc[m][n][r] = 0.f;

    #pragma unroll
    for (int kc = 0; kc < 8; kc++) {
        bf16x8 a0 = *(const bf16x8*)(xa + (size_t)(l15) * CH + kc * 32 + quad * 8);
        bf16x8 a1 = *(const bf16x8*)(xa + (size_t)(16 + l15) * CH + kc * 32 + quad * 8);
        #pragma unroll
        for (int n = 0; n < 4; n++) {
            bf16x8 b = *(const bf16x8*)(Ws + (n * 16 + l15) * WSTR + kc * 32 + quad * 8);
            acc[0][n] = __builtin_amdgcn_mfma_f32_16x16x32_bf16(a0, b, acc[0][n], 0, 0, 0);
            acc[1][n] = __builtin_amdgcn_mfma_f32_16x16x32_bf16(a1, b, acc[1][n], 0, 0, 0);
        }
    }

    bool isv = (o0 >= 512);
    #pragma unroll
    for (int n = 0; n < 4; n++) {
        int o = o0 + n * 16 + l15;
        float bias = load1(qkv_b, o, f32b);
        #pragma unroll
        for (int m = 0; m < 2; m++)
            #pragma unroll
            for (int r = 0; r < 4; r++) {
                int pix = pbase + m * 16 + quad * 4 + r;
                float v = acc[m][n][r] + bias;
                if (!isv)
                    qk[((size_t)(bl * NPIX + pix)) * 512 + o] = f2bf(v);
                else
                    vt[((size_t)(bl * CH + o - 512)) * NPIX + pix] = f2bf(v);
            }
    }
}

// ---------- K4: MFMA flash attention — phase-split pipelined staging ----------
// K/V staged in alternating phases so each global load's latency hides under an
// MFMA phase. 32 Q rows/wave, shared B-fragments, KV-split bf16 partials.
__global__ __launch_bounds__(256, 2) void attn_mfma(const u16* __restrict__ qk,
                                                    const u16* __restrict__ vt,
                                                    u16* __restrict__ Opart,
                                                    float* __restrict__ lpart,
                                                    int NE, int NR) {
    __shared__ u16 Ks[ATK * KSTR];       // 16.5 KB
    __shared__ u16 Vts[CH * VSTR];       // 20 KB
    __shared__ u16 Ps[4][2][16 * PSTR];  // 10 KB
    int bl    = blockIdx.z;
    int split = blockIdx.y;
    int q0    = blockIdx.x * 128;
    int t     = threadIdx.x;
    int w     = t >> 6, lane = t & 63;
    int l15   = lane & 15, quad = lane >> 4;

    const u16* qkb = qk + (size_t)bl * NPIX * 512;
    const u16* vtb = vt + (size_t)bl * CH * NPIX;
    int kvbase = split * SPLEN;

    // Q fragments for 2 m-tiles (32 rows)
    bf16x8 qf[2][8];
    #pragma unroll
    for (int m = 0; m < 2; m++) {
        const u16* qrow = qkb + (size_t)(q0 + w * 32 + m * 16 + l15) * 512;
        #pragma unroll
        for (int kc = 0; kc < 8; kc++)
            qf[m][kc] = *(const bf16x8*)(qrow + kc * 32 + quad * 8);
    }
    f32x4 o[2][16];
    #pragma unroll
    for (int m = 0; m < 2; m++)
        #pragma unroll
        for (int i = 0; i < 16; i++)
            #pragma unroll
            for (int r = 0; r < 4; r++) o[m][i][r] = 0.f;
    float lsum[2][4] = {{0.f,0.f,0.f,0.f},{0.f,0.f,0.f,0.f}};
    const float scale = 0.0625f;

    uint4 kreg[4], vreg[4];
    // prologue: K(0) -> LDS; V(0) loads left in flight
    #pragma unroll
    for (int i = 0; i < 4; i++) {
        int e = t + i * 256;
        kreg[i] = *(const uint4*)(qkb + (size_t)(kvbase + (e >> 5)) * 512 + 256 + (e & 31) * 8);
    }
    #pragma unroll
    for (int i = 0; i < 4; i++) {
        int e = t + i * 256;
        *(uint4*)(Ks + (e >> 5) * KSTR + (e & 31) * 8) = kreg[i];
    }
    #pragma unroll
    for (int i = 0; i < 4; i++) {
        int e = t + i * 256;
        vreg[i] = *(const uint4*)(vtb + (size_t)(e >> 2) * NPIX + kvbase + (e & 3) * 8);
    }
    __syncthreads();   // Ks ready; V loads in flight

    for (int it = 0; it < NIT; it++) {
        int kvn = kvbase + (it + 1) * ATK;

        // S = Q.K^T from Ks (V(t) loads drain underneath)
        f32x4 s[2][2];
        #pragma unroll
        for (int m = 0; m < 2; m++)
            #pragma unroll
            for (int n = 0; n < 2; n++)
                #pragma unroll
                for (int r = 0; r < 4; r++) s[m][n][r] = 0.f;
        #pragma unroll
        for (int kc = 0; kc < 8; kc++) {
            bf16x8 b0 = *(const bf16x8*)(Ks + l15 * KSTR + kc * 32 + quad * 8);
            bf16x8 b1 = *(const bf16x8*)(Ks + (16 + l15) * KSTR + kc * 32 + quad * 8);
            s[0][0] = __builtin_amdgcn_mfma_f32_16x16x32_bf16(qf[0][kc], b0, s[0][0], 0, 0, 0);
            s[0][1] = __builtin_amdgcn_mfma_f32_16x16x32_bf16(qf[0][kc], b1, s[0][1], 0, 0, 0);
            s[1][0] = __builtin_amdgcn_mfma_f32_16x16x32_bf16(qf[1][kc], b0, s[1][0], 0, 0, 0);
            s[1][1] = __builtin_amdgcn_mfma_f32_16x16x32_bf16(qf[1][kc], b1, s[1][1], 0, 0, 0);
        }

        // p = exp(s/16), no max subtraction (normalized inputs -> |S| small)
        #pragma unroll
        for (int m = 0; m < 2; m++)
            #pragma unroll
            for (int r = 0; r < 4; r++) {
                float p0 = __expf(s[m][0][r] * scale);
                float p1 = __expf(s[m][1][r] * scale);
                lsum[m][r] += p0 + p1;
                Ps[w][m][(quad * 4 + r) * PSTR + l15]      = f2bf(p0);
                Ps[w][m][(quad * 4 + r) * PSTR + 16 + l15] = f2bf(p1);
            }

        // commit V(t) (loads long since issued -> latency hidden)
        #pragma unroll
        for (int i = 0; i < 4; i++) {
            int e = t + i * 256;
            *(uint4*)(Vts + (e >> 2) * VSTR + (e & 3) * 8) = vreg[i];
        }
        __syncthreads();   // Vts ready; all waves done reading Ks

        // prefetch K(t+1) (drains under PV)
        if (it + 1 < NIT) {
            #pragma unroll
            for (int i = 0; i < 4; i++) {
                int e = t + i * 256;
                kreg[i] = *(const uint4*)(qkb + (size_t)(kvn + (e >> 5)) * 512 + 256 + (e & 31) * 8);
            }
        }

        bf16x8 pf0 = *(const bf16x8*)(&Ps[w][0][l15 * PSTR + quad * 8]);
        bf16x8 pf1 = *(const bf16x8*)(&Ps[w][1][l15 * PSTR + quad * 8]);

        // PV from Vts
        #pragma unroll
        for (int dt = 0; dt < 16; dt++) {
            bf16x8 vf = *(const bf16x8*)(Vts + (dt * 16 + l15) * VSTR + quad * 8);
            o[0][dt] = __builtin_amdgcn_mfma_f32_16x16x32_bf16(pf0, vf, o[0][dt], 0, 0, 0);
            o[1][dt] = __builtin_amdgcn_mfma_f32_16x16x32_bf16(pf1, vf, o[1][dt], 0, 0, 0);
        }

        if (it + 1 < NIT) {
            // commit K(t+1) (hidden under PV), then start V(t+1) loads
            #pragma unroll
            for (int i = 0; i < 4; i++) {
                int e = t + i * 256;
                *(uint4*)(Ks + (e >> 5) * KSTR + (e & 31) * 8) = kreg[i];
            }
            __syncthreads();   // Ks ready; all waves done reading Vts
            #pragma unroll
            for (int i = 0; i < 4; i++) {
                int e = t + i * 256;
                vreg[i] = *(const uint4*)(vtb + (size_t)(e >> 2) * NPIX + kvn + (e & 3) * 8);
            }
        }
    }

    size_t rowb = (size_t)bl * NPIX + q0 + w * 32;
    u16* op = Opart + (size_t)split * NE;
    #pragma unroll
    for (int m = 0; m < 2; m++) {
        #pragma unroll
        for (int r = 0; r < 4; r++) {
            float v = lsum[m][r];
            v += __shfl_xor(v, 1); v += __shfl_xor(v, 2);
            v += __shfl_xor(v, 4); v += __shfl_xor(v, 8);
            if (l15 == 0)
                lpart[(size_t)split * NR + rowb + m * 16 + quad * 4 + r] = v;
        }
        #pragma unroll
        for (int dt = 0; dt < 16; dt++)
            #pragma unroll
            for (int r = 0; r < 4; r++)
                op[(rowb + m * 16 + quad * 4 + r) * CH + dt * 16 + l15] = f2bf(o[m][dt][r]);
    }
}

// ---------- K5: proj GEMM (MFMA; weights in LDS) + split-combine + residual ----------
// A-fragments built by summing NSPLIT bf16 partials and scaling by 1/l per row.
__global__ __launch_bounds__(256, 4) void proj_mfma(const u16* __restrict__ Opart,
                                                    const float* __restrict__ lpart,
                                                    const u16* __restrict__ wp,
                                                    const void* __restrict__ proj_b,
                                                    const void* __restrict__ x,
                                                    void* __restrict__ out,
                                                    int b0, int NE, int NR) {
    __shared__ u16 Ws[64 * WSTR];    // 33 KB
    bool f32 = detect_f32(x);
    int bl = blockIdx.z, bg = b0 + bl;
    int n0 = blockIdx.x * 128, o0 = blockIdx.y * 64;
    int t = threadIdx.x;
    int w = t >> 6, lane = t & 63;
    int l15 = lane & 15, quad = lane >> 4;
    int pbase = n0 + w * 32;

    #pragma unroll
    for (int i = 0; i < 8; i++) {
        int e = t + i * 256;
        *(uint4*)(Ws + (e >> 5) * WSTR + (e & 31) * 8) =
            *(const uint4*)(wp + (size_t)(o0 + (e >> 5)) * CH + (e & 31) * 8);
    }
    __syncthreads();

    // per-lane 1/l for the 2 m-tile rows this lane supplies (A m-index = l15)
    size_t rowg[2]; float invl[2];
    #pragma unroll
    for (int m = 0; m < 2; m++) {
        rowg[m] = (size_t)bl * NPIX + pbase + m * 16 + l15;
        float l = 0.f;
        #pragma unroll
        for (int s = 0; s < NSPLIT; s++) l += lpart[(size_t)s * NR + rowg[m]];
        invl[m] = 1.0f / l;
    }

    f32x4 acc[2][4];
    #pragma unroll
    for (int m = 0; m < 2; m++)
        #pragma unroll
        for (int n = 0; n < 4; n++)
            #pragma unroll
            for (int r = 0; r < 4; r++) acc[m][n][r] = 0.f;

    #pragma unroll
    for (int kc = 0; kc < 8; kc++) {
        bf16x8 afr[2];
        #pragma unroll
        for (int m = 0; m < 2; m++) {
            float f[8] = {0.f,0.f,0.f,0.f,0.f,0.f,0.f,0.f};
            #pragma unroll
            for (int s = 0; s < NSPLIT; s++) {
                bf16x8 v = *(const bf16x8*)(Opart + (size_t)s * NE + rowg[m] * CH + kc * 32 + quad * 8);
                #pragma unroll
                for (int j = 0; j < 8; j++) f[j] += bf2f((u16)v[j]);
            }
            bf16x8 a;
            #pragma unroll
            for (int j = 0; j < 8; j++) a[j] = (short)f2bf(f[j] * invl[m]);
            afr[m] = a;
        }
        #pragma unroll
        for (int n = 0; n < 4; n++) {
            bf16x8 b = *(const bf16x8*)(Ws + (n * 16 + l15) * WSTR + kc * 32 + quad * 8);
            acc[0][n] = __builtin_amdgcn_mfma_f32_16x16x32_bf16(afr[0], b, acc[0][n], 0, 0, 0);
            acc[1][n] = __builtin_amdgcn_mfma_f32_16x16x32_bf16(afr[1], b, acc[1][n], 0, 0, 0);
        }
    }

    #pragma unroll
    for (int n = 0; n < 4; n++) {
        int o = o0 + n * 16 + l15;
        float bias = load1(proj_b, o, f32);
        size_t rowoff = ((size_t)(bg * CH + o)) * NPIX;
        #pragma unroll
        for (int m = 0; m < 2; m++)
            #pragma unroll
            for (int r = 0; r < 4; r++) {
                int pix = pbase + m * 16 + quad * 4 + r;
                float v = acc[m][n][r] + bias + load1(x, rowoff + pix, f32);
                store1(out, rowoff + pix, f32, v);
            }
    }
}

extern "C" void kernel_launch(void* const* d_in, const int* in_sizes, int n_in,
                              void* d_out, int out_size, void* d_ws, size_t ws_size,
                              hipStream_t stream) {
    const void* x      = d_in[0];
    const void* gn_w   = d_in[1];
    const void* gn_b   = d_in[2];
    const void* qkv_w  = d_in[3];
    const void* qkv_b  = d_in[4];
    const void* proj_w = d_in[5];
    const void* proj_b = d_in[6];

    char* ws = (char*)d_ws;
    float* stats = (float*)ws;                               // 1 KB
    u16* wq = (u16*)(ws + 1024);                             // 384 KB
    u16* wp = wq + 768 * 256;                                // 128 KB
    char* dyn = ws + 1024 + (768 * 256 + 256 * 256) * 2;

    const size_t per_batch = (size_t)NPIX * CH * 2           // xt
                           + (size_t)NPIX * 512 * 2          // qk
                           + (size_t)CH * NPIX * 2           // vt
                           + (size_t)NSPLIT * NPIX * CH * 2  // Opart bf16
                           + (size_t)NSPLIT * NPIX * 4;      // lpart
    const size_t need_full = 1024 + 600 * 1024 + BATCH * per_batch;  // ~66 MB
    int nb = (ws_size >= need_full) ? BATCH : 1;

    u16* xt      = (u16*)dyn;
    u16* qk      = xt + (size_t)nb * NPIX * CH;
    u16* vt      = qk + (size_t)nb * NPIX * 512;
    u16* Opart   = vt + (size_t)nb * CH * NPIX;
    float* lpart = (float*)(Opart + (size_t)NSPLIT * nb * NPIX * CH);
    int NE = nb * NPIX * CH;
    int NR = nb * NPIX;

    wconv<<<dim3(256), 256, 0, stream>>>(qkv_w, proj_w, wq, wp);

    for (int b0 = 0; b0 < BATCH; b0 += nb) {
        gn_stats<<<dim3(nb * NGROUPS), 256, 0, stream>>>(x, stats, b0);
        xgn<<<dim3(NPIX / 64, CH / 64, nb), 256, 0, stream>>>(
            x, gn_w, gn_b, stats, xt, b0);
        qkv_mfma<<<dim3(NPIX / 128, 768 / 64, nb), 256, 0, stream>>>(
            xt, wq, qkv_b, qk, vt);
        attn_mfma<<<dim3(NPIX / 128, NSPLIT, nb), 256, 0, stream>>>(
            qk, vt, Opart, lpart, NE, NR);
        proj_mfma<<<dim3(NPIX / 128, CH / 64, nb), 256, 0, stream>>>(
            Opart, lpart, wp, proj_b, x, d_out, b0, NE, NR);
    }
}

// Round 9
// 273.164 us; speedup vs baseline: 1.1683x; 1.1683x over previous
//
#include <hip/hip_runtime.h>
#include <stdint.h>

typedef unsigned short u16;
typedef __attribute__((ext_vector_type(8))) short bf16x8;   // 8 bf16 = 4 VGPRs
typedef __attribute__((ext_vector_type(4))) float f32x4;

#define BATCH   4
#define CH      256
#define NPIX    4096      // 64*64
#define NGROUPS 32
#define CPG     8
#define EPS     1e-5f

#define NSPLIT 4
#define SPLEN  (NPIX / NSPLIT)
#define ATK    32
#define NIT    (SPLEN / ATK)     // 32
#define KSTR   264        // K LDS row stride: 2-way alias only, 16B aligned
#define VSTR   40         // Vt LDS row stride
#define PSTR   40
#define WSTR   264        // weight LDS row stride

// ---------- bf16 helpers ----------
__device__ __forceinline__ float bf2f(u16 u) {
    union { uint32_t i; float f; } v; v.i = ((uint32_t)u) << 16; return v.f;
}
__device__ __forceinline__ u16 f2bf(float f) {
    union { float f; uint32_t i; } v; v.f = f;
    uint32_t x = v.i;
    uint32_t r = (x + 0x7fffu + ((x >> 16) & 1u)) >> 16;
    return (u16)r;
}
__device__ __forceinline__ void unpack2(uint32_t u, float& a, float& b) {
    union { uint32_t i; float f; } lo, hi;
    lo.i = u << 16; hi.i = u & 0xffff0000u;
    a = lo.f; b = hi.f;
}
__device__ __forceinline__ void unpack8(uint4 u, float* f) {
    unpack2(u.x, f[0], f[1]); unpack2(u.y, f[2], f[3]);
    unpack2(u.z, f[4], f[5]); unpack2(u.w, f[6], f[7]);
}

// ---------- runtime input-dtype detection (fp32 vs bf16 ambiguity) ----------
__device__ __forceinline__ bool detect_f32(const void* xv) {
    const u16* p = (const u16*)xv;
    int bad = 0;
    #pragma unroll
    for (int i = 0; i < 32; i++) {
        u16 v = p[2 * i];
        int e = (v >> 7) & 0xff;
        bad += (e < 0x68 || e > 0x90) ? 1 : 0;
    }
    return bad >= 10;
}
__device__ __forceinline__ float load1(const void* b, size_t i, bool f32) {
    return f32 ? ((const float*)b)[i] : bf2f(((const u16*)b)[i]);
}
__device__ __forceinline__ void store1(void* b, size_t i, bool f32, float v) {
    if (f32) ((float*)b)[i] = v; else ((u16*)b)[i] = f2bf(v);
}
__device__ __forceinline__ void load4v(const void* base, size_t off, bool f32, float* f) {
    if (f32) {
        float4 a = *(const float4*)((const float*)base + off);
        f[0] = a.x; f[1] = a.y; f[2] = a.z; f[3] = a.w;
    } else {
        uint2 u = *(const uint2*)((const u16*)base + off);
        unpack2(u.x, f[0], f[1]); unpack2(u.y, f[2], f[3]);
    }
}
__device__ __forceinline__ void load8v(const void* base, size_t off, bool f32, float* f) {
    if (f32) {
        const float4* p = (const float4*)((const float*)base + off);
        float4 a = p[0], b = p[1];
        f[0] = a.x; f[1] = a.y; f[2] = a.z; f[3] = a.w;
        f[4] = b.x; f[5] = b.y; f[6] = b.z; f[7] = b.w;
    } else {
        uint4 u = *(const uint4*)((const u16*)base + off);
        unpack8(u, f);
    }
}

// ---------- K0: weights -> bf16 ----------
__global__ __launch_bounds__(256) void wconv(const void* __restrict__ qkv_w,
                                             const void* __restrict__ proj_w,
                                             u16* __restrict__ wq, u16* __restrict__ wp) {
    bool f32q = detect_f32(qkv_w);
    bool f32p = detect_f32(proj_w);
    int i = blockIdx.x * 256 + threadIdx.x;
    for (int e = i; e < 768 * 256; e += 256 * 256)
        wq[e] = f2bf(load1(qkv_w, e, f32q));
    for (int e = i; e < 256 * 256; e += 256 * 256)
        wp[e] = f2bf(load1(proj_w, e, f32p));
}

// ---------- K1: GroupNorm stats ----------
__global__ __launch_bounds__(256) void gn_stats(const void* __restrict__ x,
                                                float* __restrict__ stats, int b0) {
    bool f32 = detect_f32(x);
    int bg = b0 * NGROUPS + blockIdx.x;
    int t  = threadIdx.x;
    size_t base = (size_t)bg * (CPG * NPIX);
    float s = 0.f, s2 = 0.f;
    for (int i = t * 8; i < CPG * NPIX; i += 256 * 8) {
        float f[8]; load8v(x, base + i, f32, f);
        #pragma unroll
        for (int e = 0; e < 8; e++) { s += f[e]; s2 += f[e] * f[e]; }
    }
    #pragma unroll
    for (int off = 1; off < 64; off <<= 1) {
        s  += __shfl_xor(s,  off);
        s2 += __shfl_xor(s2, off);
    }
    __shared__ float red[8];
    int w = t >> 6;
    if ((t & 63) == 0) { red[w * 2] = s; red[w * 2 + 1] = s2; }
    __syncthreads();
    if (t == 0) {
        float S  = red[0] + red[2] + red[4] + red[6];
        float S2 = red[1] + red[3] + red[5] + red[7];
        float n  = (float)(CPG * NPIX);
        float mu = S / n;
        float var = S2 / n - mu * mu;
        stats[bg * 2]     = mu;
        stats[bg * 2 + 1] = rsqrtf(var + EPS);
    }
}

// ---------- K2: GN-apply + transpose: x[c][n] -> xt[n][c] normalized bf16 ----------
__global__ __launch_bounds__(256) void xgn(const void* __restrict__ x,
                                           const void* __restrict__ gn_w,
                                           const void* __restrict__ gn_b,
                                           const float* __restrict__ stats,
                                           u16* __restrict__ xt, int b0) {
    bool f32 = detect_f32(x);
    __shared__ u16 T[64][72];
    int bl = blockIdx.z, bg = b0 + bl;
    int n0 = blockIdx.x * 64, c0 = blockIdx.y * 64;
    int t = threadIdx.x;
    int tc = t >> 4, tn = (t & 15) * 4;
    #pragma unroll
    for (int i = 0; i < 4; i++) {
        int cl = tc + i * 16;
        int c = c0 + cl;
        int g = c >> 3;
        float mu = stats[(bg * NGROUPS + g) * 2];
        float rs = stats[(bg * NGROUPS + g) * 2 + 1];
        float wv = load1(gn_w, c, f32) * rs;
        float bv = load1(gn_b, c, f32) - mu * wv;
        float a[4];
        load4v(x, ((size_t)(bg * CH + c)) * NPIX + n0 + tn, f32, a);
        #pragma unroll
        for (int j = 0; j < 4; j++) T[cl][tn + j] = f2bf(a[j] * wv + bv);
    }
    __syncthreads();
    #pragma unroll
    for (int i = 0; i < 2; i++) {
        int e = t + i * 256;
        int nl = e >> 3, cc = (e & 7) * 8;
        union { uint4 v; u16 s[8]; } pk;
        #pragma unroll
        for (int j = 0; j < 8; j++) pk.s[j] = T[cc + j][nl];
        *(uint4*)(xt + ((size_t)(bl * NPIX) + n0 + nl) * CH + c0 + cc) = pk.v;
    }
}

// ---------- K3: QKV GEMM (MFMA; weights in LDS, A direct-global contiguous) ----------
// V stored kv-permuted within 32-groups: pos = base32 + ((j&15)<<1 | (j>>4)),
// matching attn's packed-P k-indexing (k=2*l15+tile).
__global__ __launch_bounds__(256, 4) void qkv_mfma(const u16* __restrict__ xt,
                                                   const u16* __restrict__ wq,
                                                   const void* __restrict__ qkv_b,
                                                   u16* __restrict__ qk,
                                                   u16* __restrict__ vt) {
    __shared__ u16 Ws[64 * WSTR];    // 33 KB
    bool f32b = detect_f32(qkv_b);
    int bl = blockIdx.z;
    int n0 = blockIdx.x * 128, o0 = blockIdx.y * 64;
    int t = threadIdx.x;
    int w = t >> 6, lane = t & 63;
    int l15 = lane & 15, quad = lane >> 4;
    int pbase = n0 + w * 32;

    #pragma unroll
    for (int i = 0; i < 8; i++) {
        int e = t + i * 256;
        *(uint4*)(Ws + (e >> 5) * WSTR + (e & 31) * 8) =
            *(const uint4*)(wq + (size_t)(o0 + (e >> 5)) * CH + (e & 31) * 8);
    }
    __syncthreads();

    const u16* xa = xt + ((size_t)(bl * NPIX + pbase)) * CH;
    f32x4 acc[2][4];
    #pragma unroll
    for (int m = 0; m < 2; m++)
        #pragma unroll
        for (int n = 0; n < 4; n++)
            #pragma unroll
            for (int r = 0; r < 4; r++) acc[m][n][r] = 0.f;

    #pragma unroll
    for (int kc = 0; kc < 8; kc++) {
        bf16x8 a0 = *(const bf16x8*)(xa + (size_t)(l15) * CH + kc * 32 + quad * 8);
        bf16x8 a1 = *(const bf16x8*)(xa + (size_t)(16 + l15) * CH + kc * 32 + quad * 8);
        #pragma unroll
        for (int n = 0; n < 4; n++) {
            bf16x8 b = *(const bf16x8*)(Ws + (n * 16 + l15) * WSTR + kc * 32 + quad * 8);
            acc[0][n] = __builtin_amdgcn_mfma_f32_16x16x32_bf16(a0, b, acc[0][n], 0, 0, 0);
            acc[1][n] = __builtin_amdgcn_mfma_f32_16x16x32_bf16(a1, b, acc[1][n], 0, 0, 0);
        }
    }

    bool isv = (o0 >= 512);
    #pragma unroll
    for (int n = 0; n < 4; n++) {
        int o = o0 + n * 16 + l15;
        float bias = load1(qkv_b, o, f32b);
        #pragma unroll
        for (int m = 0; m < 2; m++)
            #pragma unroll
            for (int r = 0; r < 4; r++) {
                int pix = pbase + m * 16 + quad * 4 + r;
                float v = acc[m][n][r] + bias;
                if (!isv) {
                    qk[((size_t)(bl * NPIX + pix)) * 512 + o] = f2bf(v);
                } else {
                    int j = pix & 31;
                    int pp = (pix & ~31) | (((j & 15) << 1) | (j >> 4));
                    vt[((size_t)(bl * CH + o - 512)) * NPIX + pp] = f2bf(v);
                }
            }
    }
}

// ---------- K4: MFMA flash attention — R7 structure + packed P roundtrip ----------
// 32 Q rows/wave, shared B-fragments, KV-split bf16 partials (no-max softmax).
__global__ __launch_bounds__(256, 2) void attn_mfma(const u16* __restrict__ qk,
                                                    const u16* __restrict__ vt,
                                                    u16* __restrict__ Opart,
                                                    float* __restrict__ lpart,
                                                    int NE, int NR) {
    __shared__ u16 Ks[ATK * KSTR];       // 16.5 KB
    __shared__ u16 Vts[CH * VSTR];       // 20 KB
    __shared__ u16 Ps[4][2][16 * PSTR];  // 10 KB
    int bl    = blockIdx.z;
    int split = blockIdx.y;
    int q0    = blockIdx.x * 128;
    int t     = threadIdx.x;
    int w     = t >> 6, lane = t & 63;
    int l15   = lane & 15, quad = lane >> 4;

    const u16* qkb = qk + (size_t)bl * NPIX * 512;
    const u16* vtb = vt + (size_t)bl * CH * NPIX;
    int kvbase = split * SPLEN;

    // Q fragments for 2 m-tiles (32 rows)
    bf16x8 qf[2][8];
    #pragma unroll
    for (int m = 0; m < 2; m++) {
        const u16* qrow = qkb + (size_t)(q0 + w * 32 + m * 16 + l15) * 512;
        #pragma unroll
        for (int kc = 0; kc < 8; kc++)
            qf[m][kc] = *(const bf16x8*)(qrow + kc * 32 + quad * 8);
    }
    f32x4 o[2][16];
    #pragma unroll
    for (int m = 0; m < 2; m++)
        #pragma unroll
        for (int i = 0; i < 16; i++)
            #pragma unroll
            for (int r = 0; r < 4; r++) o[m][i][r] = 0.f;
    float lsum[2][4] = {{0.f,0.f,0.f,0.f},{0.f,0.f,0.f,0.f}};
    const float scale = 0.0625f;

    for (int it = 0; it < NIT; it++) {
        int kv0 = kvbase + it * ATK;
        __syncthreads();
        #pragma unroll
        for (int i = 0; i < 4; i++) {
            int e = t + i * 256;
            *(uint4*)(Ks + (e >> 5) * KSTR + (e & 31) * 8) =
                *(const uint4*)(qkb + (size_t)(kv0 + (e >> 5)) * 512 + 256 + (e & 31) * 8);
        }
        #pragma unroll
        for (int i = 0; i < 4; i++) {
            int e = t + i * 256;
            *(uint4*)(Vts + (e >> 2) * VSTR + (e & 3) * 8) =
                *(const uint4*)(vtb + (size_t)(e >> 2) * NPIX + kv0 + (e & 3) * 8);
        }
        __syncthreads();

        // S = Q.K^T: 2 m-tiles x 2 n-tiles; each B-read feeds 2 MFMAs
        f32x4 s[2][2];
        #pragma unroll
        for (int m = 0; m < 2; m++)
            #pragma unroll
            for (int n = 0; n < 2; n++)
                #pragma unroll
                for (int r = 0; r < 4; r++) s[m][n][r] = 0.f;
        #pragma unroll
        for (int kc = 0; kc < 8; kc++) {
            bf16x8 b0 = *(const bf16x8*)(Ks + l15 * KSTR + kc * 32 + quad * 8);
            bf16x8 b1 = *(const bf16x8*)(Ks + (16 + l15) * KSTR + kc * 32 + quad * 8);
            s[0][0] = __builtin_amdgcn_mfma_f32_16x16x32_bf16(qf[0][kc], b0, s[0][0], 0, 0, 0);
            s[0][1] = __builtin_amdgcn_mfma_f32_16x16x32_bf16(qf[0][kc], b1, s[0][1], 0, 0, 0);
            s[1][0] = __builtin_amdgcn_mfma_f32_16x16x32_bf16(qf[1][kc], b0, s[1][0], 0, 0, 0);
            s[1][1] = __builtin_amdgcn_mfma_f32_16x16x32_bf16(qf[1][kc], b1, s[1][1], 0, 0, 0);
        }

        // p = exp(s/16); packed P write: k = 2*l15 + tile (vt is kv-permuted to match)
        #pragma unroll
        for (int m = 0; m < 2; m++)
            #pragma unroll
            for (int r = 0; r < 4; r++) {
                float p0 = __expf(s[m][0][r] * scale);
                float p1 = __expf(s[m][1][r] * scale);
                lsum[m][r] += p0 + p1;
                uint32_t pk = (uint32_t)f2bf(p0) | ((uint32_t)f2bf(p1) << 16);
                *(uint32_t*)(&Ps[w][m][(quad * 4 + r) * PSTR + 2 * l15]) = pk;
            }
        bf16x8 pf0 = *(const bf16x8*)(&Ps[w][0][l15 * PSTR + quad * 8]);
        bf16x8 pf1 = *(const bf16x8*)(&Ps[w][1][l15 * PSTR + quad * 8]);

        // PV: each V B-read feeds 2 MFMAs
        #pragma unroll
        for (int dt = 0; dt < 16; dt++) {
            bf16x8 vf = *(const bf16x8*)(Vts + (dt * 16 + l15) * VSTR + quad * 8);
            o[0][dt] = __builtin_amdgcn_mfma_f32_16x16x32_bf16(pf0, vf, o[0][dt], 0, 0, 0);
            o[1][dt] = __builtin_amdgcn_mfma_f32_16x16x32_bf16(pf1, vf, o[1][dt], 0, 0, 0);
        }
    }

    size_t rowb = (size_t)bl * NPIX + q0 + w * 32;
    u16* op = Opart + (size_t)split * NE;
    #pragma unroll
    for (int m = 0; m < 2; m++) {
        #pragma unroll
        for (int r = 0; r < 4; r++) {
            float v = lsum[m][r];
            v += __shfl_xor(v, 1); v += __shfl_xor(v, 2);
            v += __shfl_xor(v, 4); v += __shfl_xor(v, 8);
            if (l15 == 0)
                lpart[(size_t)split * NR + rowb + m * 16 + quad * 4 + r] = v;
        }
        #pragma unroll
        for (int dt = 0; dt < 16; dt++)
            #pragma unroll
            for (int r = 0; r < 4; r++)
                op[(rowb + m * 16 + quad * 4 + r) * CH + dt * 16 + l15] = f2bf(o[m][dt][r]);
    }
}

// ---------- K5: proj GEMM (MFMA; weights in LDS) + split-combine + residual ----------
__global__ __launch_bounds__(256, 4) void proj_mfma(const u16* __restrict__ Opart,
                                                    const float* __restrict__ lpart,
                                                    const u16* __restrict__ wp,
                                                    const void* __restrict__ proj_b,
                                                    const void* __restrict__ x,
                                                    void* __restrict__ out,
                                                    int b0, int NE, int NR) {
    __shared__ u16 Ws[64 * WSTR];    // 33 KB
    bool f32 = detect_f32(x);
    int bl = blockIdx.z, bg = b0 + bl;
    int n0 = blockIdx.x * 128, o0 = blockIdx.y * 64;
    int t = threadIdx.x;
    int w = t >> 6, lane = t & 63;
    int l15 = lane & 15, quad = lane >> 4;
    int pbase = n0 + w * 32;

    #pragma unroll
    for (int i = 0; i < 8; i++) {
        int e = t + i * 256;
        *(uint4*)(Ws + (e >> 5) * WSTR + (e & 31) * 8) =
            *(const uint4*)(wp + (size_t)(o0 + (e >> 5)) * CH + (e & 31) * 8);
    }
    __syncthreads();

    // per-lane 1/l for the 2 m-tile rows this lane supplies (A m-index = l15)
    size_t rowg[2]; float invl[2];
    #pragma unroll
    for (int m = 0; m < 2; m++) {
        rowg[m] = (size_t)bl * NPIX + pbase + m * 16 + l15;
        float l = 0.f;
        #pragma unroll
        for (int s = 0; s < NSPLIT; s++) l += lpart[(size_t)s * NR + rowg[m]];
        invl[m] = 1.0f / l;
    }

    f32x4 acc[2][4];
    #pragma unroll
    for (int m = 0; m < 2; m++)
        #pragma unroll
        for (int n = 0; n < 4; n++)
            #pragma unroll
            for (int r = 0; r < 4; r++) acc[m][n][r] = 0.f;

    #pragma unroll
    for (int kc = 0; kc < 8; kc++) {
        bf16x8 afr[2];
        #pragma unroll
        for (int m = 0; m < 2; m++) {
            float f[8] = {0.f,0.f,0.f,0.f,0.f,0.f,0.f,0.f};
            #pragma unroll
            for (int s = 0; s < NSPLIT; s++) {
                bf16x8 v = *(const bf16x8*)(Opart + (size_t)s * NE + rowg[m] * CH + kc * 32 + quad * 8);
                #pragma unroll
                for (int j = 0; j < 8; j++) f[j] += bf2f((u16)v[j]);
            }
            bf16x8 a;
            #pragma unroll
            for (int j = 0; j < 8; j++) a[j] = (short)f2bf(f[j] * invl[m]);
            afr[m] = a;
        }
        #pragma unroll
        for (int n = 0; n < 4; n++) {
            bf16x8 b = *(const bf16x8*)(Ws + (n * 16 + l15) * WSTR + kc * 32 + quad * 8);
            acc[0][n] = __builtin_amdgcn_mfma_f32_16x16x32_bf16(afr[0], b, acc[0][n], 0, 0, 0);
            acc[1][n] = __builtin_amdgcn_mfma_f32_16x16x32_bf16(afr[1], b, acc[1][n], 0, 0, 0);
        }
    }

    #pragma unroll
    for (int n = 0; n < 4; n++) {
        int o = o0 + n * 16 + l15;
        float bias = load1(proj_b, o, f32);
        size_t rowoff = ((size_t)(bg * CH + o)) * NPIX;
        #pragma unroll
        for (int m = 0; m < 2; m++)
            #pragma unroll
            for (int r = 0; r < 4; r++) {
                int pix = pbase + m * 16 + quad * 4 + r;
                float v = acc[m][n][r] + bias + load1(x, rowoff + pix, f32);
                store1(out, rowoff + pix, f32, v);
            }
    }
}

extern "C" void kernel_launch(void* const* d_in, const int* in_sizes, int n_in,
                              void* d_out, int out_size, void* d_ws, size_t ws_size,
                              hipStream_t stream) {
    const void* x      = d_in[0];
    const void* gn_w   = d_in[1];
    const void* gn_b   = d_in[2];
    const void* qkv_w  = d_in[3];
    const void* qkv_b  = d_in[4];
    const void* proj_w = d_in[5];
    const void* proj_b = d_in[6];

    char* ws = (char*)d_ws;
    float* stats = (float*)ws;                               // 1 KB
    u16* wq = (u16*)(ws + 1024);                             // 384 KB
    u16* wp = wq + 768 * 256;                                // 128 KB
    char* dyn = ws + 1024 + (768 * 256 + 256 * 256) * 2;

    const size_t per_batch = (size_t)NPIX * CH * 2           // xt
                           + (size_t)NPIX * 512 * 2          // qk
                           + (size_t)CH * NPIX * 2           // vt
                           + (size_t)NSPLIT * NPIX * CH * 2  // Opart bf16
                           + (size_t)NSPLIT * NPIX * 4;      // lpart
    const size_t need_full = 1024 + 600 * 1024 + BATCH * per_batch;  // ~66 MB
    int nb = (ws_size >= need_full) ? BATCH : 1;

    u16* xt      = (u16*)dyn;
    u16* qk      = xt + (size_t)nb * NPIX * CH;
    u16* vt      = qk + (size_t)nb * NPIX * 512;
    u16* Opart   = vt + (size_t)nb * CH * NPIX;
    float* lpart = (float*)(Opart + (size_t)NSPLIT * nb * NPIX * CH);
    int NE = nb * NPIX * CH;
    int NR = nb * NPIX;

    wconv<<<dim3(256), 256, 0, stream>>>(qkv_w, proj_w, wq, wp);

    for (int b0 = 0; b0 < BATCH; b0 += nb) {
        gn_stats<<<dim3(nb * NGROUPS), 256, 0, stream>>>(x, stats, b0);
        xgn<<<dim3(NPIX / 64, CH / 64, nb), 256, 0, stream>>>(
            x, gn_w, gn_b, stats, xt, b0);
        qkv_mfma<<<dim3(NPIX / 128, 768 / 64, nb), 256, 0, stream>>>(
            xt, wq, qkv_b, qk, vt);
        attn_mfma<<<dim3(NPIX / 128, NSPLIT, nb), 256, 0, stream>>>(
            qk, vt, Opart, lpart, NE, NR);
        proj_mfma<<<dim3(NPIX / 128, CH / 64, nb), 256, 0, stream>>>(
            Opart, lpart, wp, proj_b, x, d_out, b0, NE, NR);
    }
}